// Round 4
// baseline (2453.628 us; speedup 1.0000x reference)
//
#include <hip/hip_runtime.h>
#include <cstdint>
#include <cstddef>

#define HID 1024
#define NB 256
#define NCAT 80
#define ROWS (NB*NCAT)   // 20480
#define PADL 511

typedef short short8_t __attribute__((ext_vector_type(8)));
typedef float f32x4_t __attribute__((ext_vector_type(4)));
typedef unsigned short u16;
typedef u16 u16x8_t __attribute__((ext_vector_type(8)));
typedef u16 u16x4_t __attribute__((ext_vector_type(4)));
typedef float f32x4v_t __attribute__((ext_vector_type(4)));

typedef const __attribute__((address_space(1))) unsigned int guint_t;
typedef __attribute__((address_space(3))) unsigned int luint_t;

__device__ __forceinline__ void gl_lds16(const void* g, void* l) {
  __builtin_amdgcn_global_load_lds((guint_t*)g, (luint_t*)l, 16, 0, 0);
}

__device__ __forceinline__ u16 f2bf(float f) {
  unsigned u = __float_as_uint(f);
  u += 0x7fffu + ((u >> 16) & 1u);   // RNE (no NaN in this problem)
  return (u16)(u >> 16);
}
__device__ __forceinline__ float bf2f(u16 s) {
  return __uint_as_float(((unsigned)s) << 16);
}

__device__ __forceinline__ f32x4_t mfma16(short8_t a, short8_t b, f32x4_t c) {
  return __builtin_amdgcn_mfma_f32_16x16x32_bf16(a, b, c, 0, 0, 0);
}

// ---------------- weight fp32 -> bf16 conversion ----------------
__global__ void cvt_w_kernel(const float* __restrict__ W1, const float* __restrict__ Wih,
                             const float* __restrict__ Whh, u16* __restrict__ W1b,
                             u16* __restrict__ Wihb, u16* __restrict__ Whhb) {
  int idx = blockIdx.x * 256 + threadIdx.x;  // each handles 4 floats
  const float* src; u16* dst; int off;
  if (idx < 262144) { src = W1; dst = W1b; off = idx; }
  else if (idx < 1048576) { src = Wih; dst = Wihb; off = idx - 262144; }
  else { src = Whh; dst = Whhb; off = idx - 1048576; }
  f32x4v_t v = reinterpret_cast<const f32x4v_t*>(src)[off];
  u16 o0 = f2bf(v[0]), o1 = f2bf(v[1]), o2 = f2bf(v[2]), o3 = f2bf(v[3]);
  u16* d = dst + (size_t)off * 4;
  d[0] = o0; d[1] = o1; d[2] = o2; d[3] = o3;
}

// ---------------- iter1 m: m = relu(x * W1[:,511] + b1) ----------------
__global__ void m1_kernel(const float* __restrict__ x, const float* __restrict__ W1,
                          const float* __restrict__ b1, u16* __restrict__ mb) {
  long idx = (long)blockIdx.x * 256 + threadIdx.x;
  long e = idx * 8;
  int r = (int)(e >> 10); int c0 = (int)(e & 1023);
  float xv = x[r];
  u16x8_t o;
#pragma unroll
  for (int j = 0; j < 8; j++) {
    int c = c0 + j;
    float v = xv * W1[(size_t)c * 1024 + PADL] + b1[c];
    o[j] = f2bf(v > 0.f ? v : 0.f);
  }
  *reinterpret_cast<u16x8_t*>(mb + e) = o;
}

// ---------------- fused: per-batch segment sum + msg = (S - m)/79 in place ----------------
__global__ void seg_msg_kernel(u16* __restrict__ mb) {
  int b = blockIdx.x;
  int c0 = blockIdx.y * 512 + threadIdx.x * 4;
  u16* base = mb + (size_t)b * (NCAT * 1024) + c0;
  float s0 = 0.f, s1 = 0.f, s2 = 0.f, s3 = 0.f;
#pragma unroll 4
  for (int n = 0; n < NCAT; n++) {
    u16x4_t v = *reinterpret_cast<const u16x4_t*>(base + (size_t)n * 1024);
    s0 += bf2f(v[0]); s1 += bf2f(v[1]); s2 += bf2f(v[2]); s3 += bf2f(v[3]);
  }
  const float inv = 1.0f / (NCAT - 1);
#pragma unroll 4
  for (int n = 0; n < NCAT; n++) {
    u16x4_t v = *reinterpret_cast<const u16x4_t*>(base + (size_t)n * 1024);
    u16x4_t o;
    o[0] = f2bf((s0 - bf2f(v[0])) * inv);
    o[1] = f2bf((s1 - bf2f(v[1])) * inv);
    o[2] = f2bf((s2 - bf2f(v[2])) * inv);
    o[3] = f2bf((s3 - bf2f(v[3])) * inv);
    *reinterpret_cast<u16x4_t*>(base + (size_t)n * 1024) = o;
  }
}

// ---------------- m GEMM (iters 2,3): m = relu(h @ W1^T + b1) -> bf16 ----------------
// 128x128 tile, BK=64, counted-vmcnt raw-barrier double-buffer pipeline.
// Each thread stages exactly 8 x 16B chunks per tile (4 A + 4 W).
__launch_bounds__(256, 4)
__global__ void gemm_m_kernel(const u16* __restrict__ hb, const u16* __restrict__ W1b,
                              const float* __restrict__ b1, u16* __restrict__ mb) {
  __shared__ __attribute__((aligned(128))) char lds[65536];   // 2 x (16KB A + 16KB B)
  const int tid = threadIdx.x;
  const int rb = blockIdx.x, nb = blockIdx.y;
  const int wid = tid >> 6, lane = tid & 63;
  const int wr = wid >> 1, wc = wid & 1;
  const int lr = lane & 15, ls = lane >> 4;

  // staging: r = tid>>3 in [0,32), slot = tid&7; rows r+32i, same (row&7) for all i
  const int r0 = tid >> 3;
  const int sp16 = (((tid & 7) ^ (r0 & 7)) << 4);
  const char* sA[4]; const char* sW[4];
#pragma unroll
  for (int i = 0; i < 4; i++) {
    sA[i] = (const char*)hb + ((size_t)(rb * 128 + 32 * i + r0) << 11) + sp16;
    sW[i] = (const char*)W1b + ((size_t)(nb * 128 + 32 * i + r0) << 11) + sp16;
  }
  const int dA0 = tid * 16, dW0 = 16384 + tid * 16;

#define MSTAGE(BUF) do { \
    _Pragma("unroll") for (int i = 0; i < 4; i++) { gl_lds16(sA[i], (BUF) + dA0 + i * 4096); sA[i] += 128; } \
    _Pragma("unroll") for (int i = 0; i < 4; i++) { gl_lds16(sW[i], (BUF) + dW0 + i * 4096); sW[i] += 128; } \
  } while (0)

  f32x4_t acc[4][4];
  f32x4_t z4 = {0.f, 0.f, 0.f, 0.f};
#pragma unroll
  for (int m2 = 0; m2 < 4; m2++)
#pragma unroll
    for (int n2 = 0; n2 < 4; n2++) acc[m2][n2] = z4;

#define MCOMP(BUF, KK) do { \
    short8_t a_[4], b_[4]; \
    const int gr_ = ((((KK) * 4 + ls) ^ (lr & 7)) << 4); \
    _Pragma("unroll") for (int m2 = 0; m2 < 4; m2++) \
      a_[m2] = *reinterpret_cast<const short8_t*>((BUF) + (wr * 64 + m2 * 16 + lr) * 128 + gr_); \
    _Pragma("unroll") for (int n2 = 0; n2 < 4; n2++) \
      b_[n2] = *reinterpret_cast<const short8_t*>((BUF) + 16384 + (wc * 64 + n2 * 16 + lr) * 128 + gr_); \
    __builtin_amdgcn_s_setprio(1); \
    _Pragma("unroll") for (int m2 = 0; m2 < 4; m2++) \
    _Pragma("unroll") for (int n2 = 0; n2 < 4; n2++) \
      acc[m2][n2] = mfma16(a_[m2], b_[n2], acc[m2][n2]); \
    __builtin_amdgcn_s_setprio(0); \
  } while (0)

  MSTAGE(lds);           // tile 0
  MSTAGE(lds + 32768);   // tile 1
  asm volatile("s_waitcnt vmcnt(8)" ::: "memory");
  __builtin_amdgcn_s_barrier();

  for (int t = 0; t < 16; t++) {
    char* bc = lds + (t & 1) * 32768;
    MCOMP(bc, 0);
    MCOMP(bc, 1);
    __builtin_amdgcn_s_barrier();
    if (t + 2 < 16) {
      MSTAGE(bc);
      asm volatile("s_waitcnt vmcnt(8)" ::: "memory");
    } else if (t + 2 == 16) {
      asm volatile("s_waitcnt vmcnt(0)" ::: "memory");
    }
    __builtin_amdgcn_s_barrier();
  }
#undef MSTAGE
#undef MCOMP

#pragma unroll
  for (int m2 = 0; m2 < 4; m2++)
#pragma unroll
    for (int n2 = 0; n2 < 4; n2++) {
      int col = nb * 128 + wc * 64 + n2 * 16 + lr;
      float bias = b1[col];
#pragma unroll
      for (int j = 0; j < 4; j++) {
        int gr = rb * 128 + wr * 64 + m2 * 16 + ls * 4 + j;
        float v = acc[m2][n2][j] + bias;
        mb[(size_t)gr * 1024 + col] = f2bf(v > 0.f ? v : 0.f);
      }
    }
}

// ---------------- fused gates GEMM + GRU ----------------
// BM=256 rows x 64 hidden cols x 3 gates. 8 waves 4M x 2N (wave tile 64x32/gate).
// BK=64: A tile 256x64 (32KB), W tile 192x64 (24KB) -> 56KB/tile, dbuf 112KB.
// Every thread stages exactly 7 x 16B chunks/tile -> uniform counted vmcnt(7).
// Raw-barrier pipeline: loads for tile t+2 stay in flight across barriers.
template <int NSEG>   // 1 = first iteration (rank-1 h), 2 = general
__launch_bounds__(512, 2)
__global__ void gru_kernel(const u16* __restrict__ msgb, const u16* __restrict__ hbin,
                           const u16* __restrict__ Wihb, const u16* __restrict__ Whhb,
                           const float* __restrict__ bih, const float* __restrict__ bhh,
                           const float* __restrict__ x, const float* __restrict__ WhhF,
                           float* __restrict__ hf, u16* __restrict__ hbout) {
  __shared__ __attribute__((aligned(128))) char lds[114688];
  const int tid = threadIdx.x;
  const int rb = blockIdx.x;        // 80 row-blocks of 256
  const int hb0 = blockIdx.y * 64;
  const int wid = tid >> 6, lane = tid & 63;
  const int mw = wid >> 1, nw = wid & 1;   // 4M x 2N waves
  const int lr = lane & 15, ls = lane >> 4;

  // staging: r = tid>>3 in [0,64), slot = tid&7
  const int r0 = tid >> 3;
  const int sp16 = (((tid & 7) ^ (r0 & 7)) << 4);
  const char* sA[4]; const char* sW[3];
#pragma unroll
  for (int i = 0; i < 4; i++)
    sA[i] = (const char*)msgb + ((size_t)(rb * 256 + 64 * i + r0) << 11) + sp16;
#pragma unroll
  for (int g = 0; g < 3; g++)
    sW[g] = (const char*)Wihb + ((size_t)(g * 1024 + hb0 + r0) << 11) + sp16;
  const int dA0 = tid * 16, dW0 = 32768 + tid * 16;

#define GSTAGE(BUF) do { \
    _Pragma("unroll") for (int i = 0; i < 4; i++) { gl_lds16(sA[i], (BUF) + dA0 + i * 8192); sA[i] += 128; } \
    _Pragma("unroll") for (int g = 0; g < 3; g++) { gl_lds16(sW[g], (BUF) + dW0 + g * 8192); sW[g] += 128; } \
  } while (0)

  f32x4_t ar[4][2], az[4][2], an0[4][2], an1[4][2];
  f32x4_t z4 = {0.f, 0.f, 0.f, 0.f};
#pragma unroll
  for (int m = 0; m < 4; m++)
#pragma unroll
    for (int n = 0; n < 2; n++) { ar[m][n] = z4; az[m][n] = z4; an0[m][n] = z4; an1[m][n] = z4; }

#define GCOMP(BUF, KK, AN) do { \
    short8_t a_[4], bR_[2], bZ_[2], bN_[2]; \
    const int gr_ = ((((KK) * 4 + ls) ^ (lr & 7)) << 4); \
    _Pragma("unroll") for (int m = 0; m < 4; m++) \
      a_[m] = *reinterpret_cast<const short8_t*>((BUF) + (mw * 64 + m * 16 + lr) * 128 + gr_); \
    _Pragma("unroll") for (int n = 0; n < 2; n++) { \
      const int rr_ = nw * 32 + n * 16 + lr; \
      bR_[n] = *reinterpret_cast<const short8_t*>((BUF) + 32768 + rr_ * 128 + gr_); \
      bZ_[n] = *reinterpret_cast<const short8_t*>((BUF) + 32768 + (64 + rr_) * 128 + gr_); \
      bN_[n] = *reinterpret_cast<const short8_t*>((BUF) + 32768 + (128 + rr_) * 128 + gr_); } \
    __builtin_amdgcn_s_setprio(1); \
    _Pragma("unroll") for (int m = 0; m < 4; m++) \
    _Pragma("unroll") for (int n = 0; n < 2; n++) { \
      ar[m][n] = mfma16(a_[m], bR_[n], ar[m][n]); \
      az[m][n] = mfma16(a_[m], bZ_[n], az[m][n]); \
      AN[m][n] = mfma16(a_[m], bN_[n], AN[m][n]); } \
    __builtin_amdgcn_s_setprio(0); \
  } while (0)

  GSTAGE(lds);            // tile 0
  GSTAGE(lds + 57344);    // tile 1
  asm volatile("s_waitcnt vmcnt(7)" ::: "memory");
  __builtin_amdgcn_s_barrier();

  const int NT = NSEG * 16;
  for (int t = 0; t < NT; t++) {
    char* bc = lds + (t & 1) * 57344;
    if (NSEG == 2 && t >= 16) {
      GCOMP(bc, 0, an1);
      GCOMP(bc, 1, an1);
    } else {
      GCOMP(bc, 0, an0);
      GCOMP(bc, 1, an0);
    }
    __builtin_amdgcn_s_barrier();
    if (t + 2 < NT) {
      if (NSEG == 2 && t == 14) {
        const ptrdiff_t jA = (const char*)hbin - (const char*)msgb - 2048;
        const ptrdiff_t jW = (const char*)Whhb - (const char*)Wihb - 2048;
#pragma unroll
        for (int i = 0; i < 4; i++) sA[i] += jA;
#pragma unroll
        for (int g = 0; g < 3; g++) sW[g] += jW;
      }
      GSTAGE(bc);
      asm volatile("s_waitcnt vmcnt(7)" ::: "memory");
    } else if (t + 2 == NT) {
      asm volatile("s_waitcnt vmcnt(0)" ::: "memory");
    }
    __builtin_amdgcn_s_barrier();
  }
#undef GSTAGE
#undef GCOMP

  // ---- epilogue: GRU update ----
#pragma unroll
  for (int n2 = 0; n2 < 2; n2++) {
    int ch = hb0 + nw * 32 + n2 * 16 + lr;
    float br_ = bih[ch] + bhh[ch];
    float bz_ = bih[1024 + ch] + bhh[1024 + ch];
    float bin_ = bih[2048 + ch];
    float bhn_ = bhh[2048 + ch];
    float wr511 = 0.f, wz511 = 0.f, wn511 = 0.f;
    if (NSEG == 1) {
      wr511 = WhhF[(size_t)ch * 1024 + PADL];
      wz511 = WhhF[(size_t)(1024 + ch) * 1024 + PADL];
      wn511 = WhhF[(size_t)(2048 + ch) * 1024 + PADL];
    }
#pragma unroll
    for (int m = 0; m < 4; m++)
#pragma unroll
      for (int j = 0; j < 4; j++) {
        int gr = rb * 256 + mw * 64 + m * 16 + ls * 4 + j;
        float vr = ar[m][n2][j] + br_;
        float vz = az[m][n2][j] + bz_;
        float vin = an0[m][n2][j] + bin_;
        float vhn, hold;
        if (NSEG == 1) {
          float xv = x[gr];
          vr += xv * wr511;
          vz += xv * wz511;
          vhn = xv * wn511 + bhn_;
          hold = (ch == PADL) ? xv : 0.f;
        } else {
          vhn = an1[m][n2][j] + bhn_;
          hold = hf[(size_t)gr * 1024 + ch];
        }
        float rg = 1.f / (1.f + __expf(-vr));
        float zg = 1.f / (1.f + __expf(-vz));
        float ng = tanhf(vin + rg * vhn);
        float hnew = (1.f - zg) * ng + zg * hold;
        hf[(size_t)gr * 1024 + ch] = hnew;
        hbout[(size_t)gr * 1024 + ch] = f2bf(hnew);
      }
  }
}

// ---------------- out = h . w_s + b_s ----------------
__global__ void out_proj_kernel(const float* __restrict__ hf, const float* __restrict__ wsv,
                                const float* __restrict__ bs, float* __restrict__ out) {
  int row = blockIdx.x * 4 + (threadIdx.x >> 6);
  int lane = threadIdx.x & 63;
  const float* p = hf + (size_t)row * 1024;
  float s = 0.f;
#pragma unroll
  for (int t = 0; t < 16; t++) s += p[lane + t * 64] * wsv[lane + t * 64];
#pragma unroll
  for (int off = 32; off; off >>= 1) s += __shfl_down(s, off);
  if (lane == 0) out[row] = s + bs[0];
}

extern "C" void kernel_launch(void* const* d_in, const int* in_sizes, int n_in,
                              void* d_out, int out_size, void* d_ws, size_t ws_size,
                              hipStream_t stream) {
  const float* x = (const float*)d_in[0];
  const float* W1 = (const float*)d_in[1];
  const float* b1 = (const float*)d_in[2];
  const float* Wih = (const float*)d_in[3];
  const float* Whh = (const float*)d_in[4];
  const float* bih = (const float*)d_in[5];
  const float* bhh = (const float*)d_in[6];
  const float* wsv = (const float*)d_in[7];
  const float* bs = (const float*)d_in[8];
  float* out = (float*)d_out;

  char* wsp = (char*)d_ws;
  size_t off = 0;
  auto alloc = [&](size_t bytes) { void* p = wsp + off; off += (bytes + 255) & ~(size_t)255; return p; };
  float* hf = (float*)alloc((size_t)ROWS * 1024 * 4);
  u16* hbA = (u16*)alloc((size_t)ROWS * 1024 * 2);
  u16* hbB = (u16*)alloc((size_t)ROWS * 1024 * 2);
  u16* mb = (u16*)alloc((size_t)ROWS * 1024 * 2);
  u16* W1b = (u16*)alloc((size_t)1024 * 1024 * 2);
  u16* Wihb = (u16*)alloc((size_t)3072 * 1024 * 2);
  u16* Whhb = (u16*)alloc((size_t)3072 * 1024 * 2);

  cvt_w_kernel<<<7168, 256, 0, stream>>>(W1, Wih, Whh, W1b, Wihb, Whhb);

  // ---- iteration 1 (rank-1 hidden state, specialized) ----
  m1_kernel<<<10240, 256, 0, stream>>>(x, W1, b1, mb);
  seg_msg_kernel<<<dim3(NB, 2), 128, 0, stream>>>(mb);
  gru_kernel<1><<<dim3(80, 16), 512, 0, stream>>>(mb, nullptr, Wihb, Whhb, bih, bhh, x, Whh, hf, hbA);

  // ---- iterations 2..T ----
  for (int it = 1; it < 3; it++) {
    u16* hin = (it & 1) ? hbA : hbB;
    u16* hout = (it & 1) ? hbB : hbA;
    gemm_m_kernel<<<dim3(160, 8), 256, 0, stream>>>(hin, W1b, b1, mb);
    seg_msg_kernel<<<dim3(NB, 2), 128, 0, stream>>>(mb);
    gru_kernel<2><<<dim3(80, 16), 512, 0, stream>>>(mb, hin, Wihb, Whhb, bih, bhh, x, Whh, hf, hout);
  }

  out_proj_kernel<<<5120, 256, 0, stream>>>(hf, wsv, bs, out);
}